// Round 1
// baseline (1447.180 us; speedup 1.0000x reference)
//
#include <hip/hip_runtime.h>
#include <math.h>

#define NPTS 2048
#define KNN 20
#define EPS_BN 1e-5f

// ============================================================
// xx[b][n] = sum_c x[b][c][n]^2
// grid (NPTS/256, B), block 256
// ============================================================
__global__ __launch_bounds__(256) void xx_kernel(const float* __restrict__ xin,
                                                 long bstride,
                                                 float* __restrict__ xx, int C) {
    int b = blockIdx.y;
    int n = blockIdx.x * 256 + threadIdx.x;
    const float* xb = xin + (long)b * bstride;
    float s = 0.f;
    for (int c = 0; c < C; ++c) {
        float v = xb[(long)c * NPTS + n];
        s = fmaf(v, v, s);
    }
    xx[(long)b * NPTS + n] = s;
}

// ============================================================
// Pairwise distances + top-k (k=20 smallest, tie -> smaller index).
// Block handles 8 rows (n) x all 2048 cols (m). 256 threads.
// acc in registers (8 rows x 8 cols/thread); dist staged 4 rows at a
// time in LDS; each wave selects one row fully in registers.
// grid (NPTS/8, B)
// ============================================================
__global__ __launch_bounds__(256) void dist_topk_kernel(const float* __restrict__ xin,
                                                        long bstride,
                                                        const float* __restrict__ xx,
                                                        int* __restrict__ idxout, int C) {
    __shared__ float dist_s[4 * NPTS];   // 32 KB
    __shared__ float xn_s[128 * 8];      // [c][r], C<=128
    int b = blockIdx.y;
    int n0 = blockIdx.x * 8;
    int tid = threadIdx.x;
    const float* xb = xin + (long)b * bstride;

    for (int i = tid; i < C * 8; i += 256) {
        int c = i >> 3, r = i & 7;
        xn_s[i] = xb[(long)c * NPTS + n0 + r];
    }
    __syncthreads();

    float acc[8][8];
#pragma unroll
    for (int r = 0; r < 8; ++r)
#pragma unroll
        for (int i = 0; i < 8; ++i) acc[r][i] = 0.f;

    for (int c = 0; c < C; ++c) {
        const float* row = xb + (long)c * NPTS;
        float xm[8];
#pragma unroll
        for (int i = 0; i < 8; ++i) xm[i] = row[tid + 256 * i];
        float4 a0 = *(const float4*)(xn_s + c * 8);
        float4 a1 = *(const float4*)(xn_s + c * 8 + 4);
        float xnv[8] = {a0.x, a0.y, a0.z, a0.w, a1.x, a1.y, a1.z, a1.w};
#pragma unroll
        for (int r = 0; r < 8; ++r)
#pragma unroll
            for (int i = 0; i < 8; ++i) acc[r][i] = fmaf(xnv[r], xm[i], acc[r][i]);
    }

    const float* xxb = xx + (long)b * NPTS;
    float xxm[8];
#pragma unroll
    for (int i = 0; i < 8; ++i) xxm[i] = xxb[tid + 256 * i];
    float xxn[8];
#pragma unroll
    for (int r = 0; r < 8; ++r) xxn[r] = xxb[n0 + r];

    int wave = tid >> 6, lane = tid & 63;

    for (int p = 0; p < 2; ++p) {
        __syncthreads();  // previous phase's reads from dist_s done
#pragma unroll
        for (int r4 = 0; r4 < 4; ++r4) {
            int r = p * 4 + r4;
#pragma unroll
            for (int i = 0; i < 8; ++i)
                dist_s[r4 * NPTS + tid + 256 * i] = xxn[r] + xxm[i] - 2.f * acc[r][i];
        }
        __syncthreads();
        // wave selects row (p*4 + wave), all-register selection
        int n = n0 + p * 4 + wave;
        float v[32];
#pragma unroll
        for (int i = 0; i < 32; ++i) v[i] = dist_s[wave * NPTS + lane + 64 * i];
        int* outp = idxout + ((long)b * NPTS + n) * KNN;
        for (int kk = 0; kk < KNN; ++kk) {
            float bv = v[0];
            int bi = 0;
#pragma unroll
            for (int i = 1; i < 32; ++i)
                if (v[i] < bv) { bv = v[i]; bi = i; }
            int bm = lane + 64 * bi;
#pragma unroll
            for (int off = 32; off >= 1; off >>= 1) {
                float ov = __shfl_xor(bv, off, 64);
                int om = __shfl_xor(bm, off, 64);
                if (ov < bv || (ov == bv && om < bm)) { bv = ov; bm = om; }
            }
            if (lane == 0) outp[kk] = bm;
#pragma unroll
            for (int i = 0; i < 32; ++i)
                if (bm == lane + 64 * i) v[i] = 3.0e38f;
        }
    }
}

// ============================================================
// t' = bn_scale*(W1-W2)@x + bn_bias ; u' = bn_scale*W2@x
// W is [O][2C] row-major. Block: 16 o x 512 n, thread: 16 o x 2 n.
// grid (NPTS/512, O/16, B)
// ============================================================
__global__ __launch_bounds__(256) void gemm_tu_kernel(
    const float* __restrict__ xin, long bstride, const float* __restrict__ W,
    const float* __restrict__ bg, const float* __restrict__ bb,
    const float* __restrict__ bm, const float* __restrict__ bv,
    float* __restrict__ tbuf, float* __restrict__ ubuf, int C, int O) {
    __shared__ float wa_s[128 * 16];  // (W1-W2)[c][ol]
    __shared__ float wb_s[128 * 16];  // W2[c][ol]
    int b = blockIdx.z;
    int o0 = blockIdx.y * 16;
    int n0 = blockIdx.x * 512;
    int tid = threadIdx.x;

    for (int i = tid; i < C * 16; i += 256) {
        int c = i >> 4, ol = i & 15;
        float w1 = W[(long)(o0 + ol) * (2 * C) + c];
        float w2 = W[(long)(o0 + ol) * (2 * C) + C + c];
        wa_s[i] = w1 - w2;
        wb_s[i] = w2;
    }
    __syncthreads();

    float ta[2][16], ua[2][16];
#pragma unroll
    for (int j = 0; j < 2; ++j)
#pragma unroll
        for (int ol = 0; ol < 16; ++ol) { ta[j][ol] = 0.f; ua[j][ol] = 0.f; }

    const float* xb = xin + (long)b * bstride;
    for (int c = 0; c < C; ++c) {
        float xv0 = xb[(long)c * NPTS + n0 + tid];
        float xv1 = xb[(long)c * NPTS + n0 + tid + 256];
        const float* wac = wa_s + c * 16;
        const float* wbc = wb_s + c * 16;
#pragma unroll
        for (int ol = 0; ol < 16; ++ol) {
            float a = wac[ol], w2 = wbc[ol];
            ta[0][ol] = fmaf(a, xv0, ta[0][ol]);
            ta[1][ol] = fmaf(a, xv1, ta[1][ol]);
            ua[0][ol] = fmaf(w2, xv0, ua[0][ol]);
            ua[1][ol] = fmaf(w2, xv1, ua[1][ol]);
        }
    }

#pragma unroll
    for (int ol = 0; ol < 16; ++ol) {
        int o = o0 + ol;
        float sc = bg[o] / sqrtf(bv[o] + EPS_BN);
        float bias = bb[o] - bm[o] * sc;
        long base = ((long)b * O + o) * NPTS + n0 + tid;
        tbuf[base] = ta[0][ol] * sc + bias;
        tbuf[base + 256] = ta[1][ol] * sc + bias;
        ubuf[base] = ua[0][ol] * sc;
        ubuf[base + 256] = ua[1][ol] * sc;
    }
}

// ============================================================
// out[b][o][n] = max_j lrelu(t'[b][o][n] + u'[b][o][idx[b][n][j]])
// Block per (o, b): u' row staged in LDS.
// grid (O, B)
// ============================================================
__global__ __launch_bounds__(256) void gather_kernel(const float* __restrict__ tbuf,
                                                     const float* __restrict__ ubuf,
                                                     const int* __restrict__ idx,
                                                     float* __restrict__ out, int O) {
    __shared__ float urow[NPTS];
    int o = blockIdx.x, b = blockIdx.y;
    int tid = threadIdx.x;
    const float4* up4 = (const float4*)(ubuf + ((long)b * O + o) * NPTS);
    float4* ur4 = (float4*)urow;
    for (int i = tid; i < NPTS / 4; i += 256) ur4[i] = up4[i];
    __syncthreads();

    const float* tp = tbuf + ((long)b * O + o) * NPTS;
    float* op = out + (long)b * (512 * NPTS) + (long)o * NPTS;
    for (int nn = 0; nn < 8; ++nn) {
        int n = nn * 256 + tid;
        float tv = tp[n];
        const int4* ip = (const int4*)(idx + ((long)b * NPTS + n) * KNN);
        float mx = -3.0e38f;
#pragma unroll
        for (int jj = 0; jj < 5; ++jj) {
            int4 i4 = ip[jj];
            float y0 = tv + urow[i4.x];
            float y1 = tv + urow[i4.y];
            float y2 = tv + urow[i4.z];
            float y3 = tv + urow[i4.w];
            y0 = y0 > 0.f ? y0 : 0.2f * y0;
            y1 = y1 > 0.f ? y1 : 0.2f * y1;
            y2 = y2 > 0.f ? y2 : 0.2f * y2;
            y3 = y3 > 0.f ? y3 : 0.2f * y3;
            mx = fmaxf(mx, fmaxf(fmaxf(y0, y1), fmaxf(y2, y3)));
        }
        op[n] = mx;
    }
}

// ============================================================
// emb = lrelu(bn5(W5 @ xc)); feat = [max_n emb, mean_n emb]
// Block: (b, 16 o) over all n. Thread: 16 o x 4 n x 2 halves.
// grid (1024/16, B)
// ============================================================
__global__ __launch_bounds__(256) void w5_reduce_kernel(
    const float* __restrict__ xc, const float* __restrict__ W5,
    const float* __restrict__ bg, const float* __restrict__ bb,
    const float* __restrict__ bm, const float* __restrict__ bv,
    float* __restrict__ feat) {
    __shared__ float w_s[512 * 16];  // 32 KB, [c][ol]
    __shared__ float rmax[4][16];
    __shared__ float rsum[4][16];
    int b = blockIdx.y;
    int o0 = blockIdx.x * 16;
    int tid = threadIdx.x;

    for (int i = tid; i < 512 * 16; i += 256) {
        int c = i >> 4, ol = i & 15;
        w_s[i] = W5[(long)(o0 + ol) * 512 + c];
    }
    __syncthreads();

    float sc[16], bi[16];
#pragma unroll
    for (int ol = 0; ol < 16; ++ol) {
        int o = o0 + ol;
        sc[ol] = bg[o] / sqrtf(bv[o] + EPS_BN);
        bi[ol] = bb[o] - bm[o] * sc[ol];
    }
    float mx[16], sm[16];
#pragma unroll
    for (int ol = 0; ol < 16; ++ol) { mx[ol] = -3.0e38f; sm[ol] = 0.f; }

    const float* xb = xc + (long)b * 512 * NPTS;
    for (int half = 0; half < 2; ++half) {
        float acc[4][16];
#pragma unroll
        for (int v = 0; v < 4; ++v)
#pragma unroll
            for (int ol = 0; ol < 16; ++ol) acc[v][ol] = 0.f;
        for (int c = 0; c < 512; ++c) {
            const float* row = xb + (long)c * NPTS + half * 1024;
            float xv0 = row[tid];
            float xv1 = row[tid + 256];
            float xv2 = row[tid + 512];
            float xv3 = row[tid + 768];
            const float* wc = w_s + c * 16;
#pragma unroll
            for (int ol = 0; ol < 16; ++ol) {
                float w = wc[ol];
                acc[0][ol] = fmaf(w, xv0, acc[0][ol]);
                acc[1][ol] = fmaf(w, xv1, acc[1][ol]);
                acc[2][ol] = fmaf(w, xv2, acc[2][ol]);
                acc[3][ol] = fmaf(w, xv3, acc[3][ol]);
            }
        }
#pragma unroll
        for (int v = 0; v < 4; ++v)
#pragma unroll
            for (int ol = 0; ol < 16; ++ol) {
                float y = acc[v][ol] * sc[ol] + bi[ol];
                y = y > 0.f ? y : 0.2f * y;
                mx[ol] = fmaxf(mx[ol], y);
                sm[ol] += y;
            }
    }

    int wave = tid >> 6, lane = tid & 63;
#pragma unroll
    for (int ol = 0; ol < 16; ++ol) {
        float m = mx[ol], s = sm[ol];
#pragma unroll
        for (int off = 32; off >= 1; off >>= 1) {
            m = fmaxf(m, __shfl_xor(m, off, 64));
            s += __shfl_xor(s, off, 64);
        }
        mx[ol] = m;
        sm[ol] = s;
    }
    if (lane == 0) {
#pragma unroll
        for (int ol = 0; ol < 16; ++ol) { rmax[wave][ol] = mx[ol]; rsum[wave][ol] = sm[ol]; }
    }
    __syncthreads();
    if (tid < 16) {
        float m = rmax[0][tid], s = rsum[0][tid];
#pragma unroll
        for (int w = 1; w < 4; ++w) { m = fmaxf(m, rmax[w][tid]); s += rsum[w][tid]; }
        feat[(long)b * 2048 + o0 + tid] = m;
        feat[(long)b * 2048 + 1024 + o0 + tid] = s * (1.f / 2048.f);
    }
}

// ============================================================
// Generic FC: out[b][o] = act(bn(in[b] . W[o]))  (wave per o)
// grid (ceil(O/4), B), block 256 = 4 waves
// ============================================================
__global__ __launch_bounds__(256) void fc_kernel(const float* __restrict__ in,
                                                 const float* __restrict__ W,
                                                 const float* __restrict__ bg,
                                                 const float* __restrict__ bb,
                                                 const float* __restrict__ bm,
                                                 const float* __restrict__ bv,
                                                 float* __restrict__ out, int I, int O,
                                                 int do_lrelu) {
    int b = blockIdx.y;
    int o = blockIdx.x * 4 + (threadIdx.x >> 6);
    int lane = threadIdx.x & 63;
    if (o < O) {
        const float* ip = in + (long)b * I;
        const float* wp = W + (long)o * I;
        float s = 0.f;
        for (int i = lane; i < I; i += 64) s = fmaf(ip[i], wp[i], s);
#pragma unroll
        for (int off = 32; off >= 1; off >>= 1) s += __shfl_xor(s, off, 64);
        if (lane == 0) {
            float y;
            if (bg) {
                float scv = bg[o] / sqrtf(bv[o] + EPS_BN);
                y = (s - bm[o]) * scv + bb[o];
                if (do_lrelu) y = y > 0.f ? y : 0.2f * y;
            } else {
                y = s + bb[o];
            }
            out[(long)b * O + o] = y;
        }
    }
}

// ============================================================
extern "C" void kernel_launch(void* const* d_in, const int* in_sizes, int n_in,
                              void* d_out, int out_size, void* d_ws, size_t ws_size,
                              hipStream_t stream) {
    const float* x = (const float*)d_in[0];
    const float* W1 = (const float*)d_in[1];
    const float* W2 = (const float*)d_in[6];
    const float* W3 = (const float*)d_in[11];
    const float* W4 = (const float*)d_in[16];
    const float* W5 = (const float*)d_in[21];
    const float* L1 = (const float*)d_in[26];
    const float* L2 = (const float*)d_in[31];
    const float* L3 = (const float*)d_in[36];
    const float* L3b = (const float*)d_in[37];

    // workspace layout
    float* xc = (float*)d_ws;                    // 8*512*2048
    float* tb = xc + (long)8 * 512 * NPTS;       // 8*256*2048
    float* ub = tb + (long)8 * 256 * NPTS;       // 8*256*2048
    int* idx = (int*)(ub + (long)8 * 256 * NPTS);  // 8*2048*20
    float* xxb = (float*)(idx + (long)8 * NPTS * KNN);  // 8*2048
    float* feat = xxb + (long)8 * NPTS;          // 8*2048
    float* h1 = feat + (long)8 * NPTS;           // 8*512
    float* h2 = h1 + (long)8 * 512;              // 8*256

    struct Layer {
        const float* xin; long bstride; const float* W;
        const float *g, *b, *m, *v; int C, O, c0;
    };
    Layer layers[4] = {
        {x, (long)3 * NPTS, W1,
         (const float*)d_in[2], (const float*)d_in[3], (const float*)d_in[4], (const float*)d_in[5],
         3, 64, 0},
        {xc, (long)512 * NPTS, W2,
         (const float*)d_in[7], (const float*)d_in[8], (const float*)d_in[9], (const float*)d_in[10],
         64, 64, 64},
        {xc + (long)64 * NPTS, (long)512 * NPTS, W3,
         (const float*)d_in[12], (const float*)d_in[13], (const float*)d_in[14], (const float*)d_in[15],
         64, 128, 128},
        {xc + (long)128 * NPTS, (long)512 * NPTS, W4,
         (const float*)d_in[17], (const float*)d_in[18], (const float*)d_in[19], (const float*)d_in[20],
         128, 256, 256},
    };

    for (int l = 0; l < 4; ++l) {
        const Layer& L = layers[l];
        xx_kernel<<<dim3(NPTS / 256, 8), 256, 0, stream>>>(L.xin, L.bstride, xxb, L.C);
        dist_topk_kernel<<<dim3(NPTS / 8, 8), 256, 0, stream>>>(L.xin, L.bstride, xxb, idx, L.C);
        gemm_tu_kernel<<<dim3(NPTS / 512, L.O / 16, 8), 256, 0, stream>>>(
            L.xin, L.bstride, L.W, L.g, L.b, L.m, L.v, tb, ub, L.C, L.O);
        gather_kernel<<<dim3(L.O, 8), 256, 0, stream>>>(tb, ub, idx, xc + (long)L.c0 * NPTS, L.O);
    }

    w5_reduce_kernel<<<dim3(1024 / 16, 8), 256, 0, stream>>>(
        xc, W5, (const float*)d_in[22], (const float*)d_in[23], (const float*)d_in[24],
        (const float*)d_in[25], feat);

    fc_kernel<<<dim3(512 / 4, 8), 256, 0, stream>>>(
        feat, L1, (const float*)d_in[27], (const float*)d_in[28], (const float*)d_in[29],
        (const float*)d_in[30], h1, 2048, 512, 1);
    fc_kernel<<<dim3(256 / 4, 8), 256, 0, stream>>>(
        h1, L2, (const float*)d_in[32], (const float*)d_in[33], (const float*)d_in[34],
        (const float*)d_in[35], h2, 512, 256, 1);
    fc_kernel<<<dim3(10, 8), 256, 0, stream>>>(
        h2, L3, nullptr, L3b, nullptr, nullptr, (float*)d_out, 256, 40, 0);
}

// Round 2
// 1315.014 us; speedup vs baseline: 1.1005x; 1.1005x over previous
//
#include <hip/hip_runtime.h>
#include <math.h>

#define NPTS 2048
#define KNN 20
#define EPS_BN 1e-5f

// ============================================================
// xx[b][n] = sum_c x[b][c][n]^2
// ============================================================
__global__ __launch_bounds__(256) void xx_kernel(const float* __restrict__ xin,
                                                 long bstride,
                                                 float* __restrict__ xx, int C) {
    int b = blockIdx.y;
    int n = blockIdx.x * 256 + threadIdx.x;
    const float* xb = xin + (long)b * bstride;
    float s = 0.f;
    for (int c = 0; c < C; ++c) {
        float v = xb[(long)c * NPTS + n];
        s = fmaf(v, v, s);
    }
    xx[(long)b * NPTS + n] = s;
}

// ============================================================
// Pairwise distances + exact top-k (k=20 smallest, tie -> smaller col).
// Block: 8 rows x 2048 cols, 256 threads, acc 8x8 in regs.
// Selection: threshold prefilter (T = max of 32 pairwise lane-min pairs
// guarantees >=32 candidates <= T), ballot-compact into reused dist_s
// region, then 20x argmin over ~2 reg slots. Exact fallback for M>512.
// grid (NPTS/8, B)
// ============================================================
__global__ __launch_bounds__(256) void dist_topk_kernel(const float* __restrict__ xin,
                                                        long bstride,
                                                        const float* __restrict__ xx,
                                                        int* __restrict__ idxout, int C) {
    __shared__ float dist_s[4 * NPTS];   // 32 KB exactly -> 5 blocks/CU
    int b = blockIdx.y;
    int n0 = blockIdx.x * 8;
    int tid = threadIdx.x;
    const float* xb = xin + (long)b * bstride;

    float acc[8][8];
#pragma unroll
    for (int r = 0; r < 8; ++r)
#pragma unroll
        for (int i = 0; i < 8; ++i) acc[r][i] = 0.f;

    for (int c = 0; c < C; ++c) {
        const float* row = xb + (long)c * NPTS;
        float xm[8];
#pragma unroll
        for (int i = 0; i < 8; ++i) xm[i] = row[tid + 256 * i];
#pragma unroll
        for (int r = 0; r < 8; ++r) {
            float xnv = row[n0 + r];  // wave-uniform -> scalar load
#pragma unroll
            for (int i = 0; i < 8; ++i) acc[r][i] = fmaf(xnv, xm[i], acc[r][i]);
        }
    }

    const float* xxb = xx + (long)b * NPTS;
    float xxm[8];
#pragma unroll
    for (int i = 0; i < 8; ++i) xxm[i] = xxb[tid + 256 * i];
    float xxn[8];
#pragma unroll
    for (int r = 0; r < 8; ++r) xxn[r] = xxb[n0 + r];  // uniform

    int wave = tid >> 6, lane = tid & 63;

    for (int p = 0; p < 2; ++p) {
        __syncthreads();  // prior phase's LDS use complete
#pragma unroll
        for (int r4 = 0; r4 < 4; ++r4) {
            int r = p * 4 + r4;
#pragma unroll
            for (int i = 0; i < 8; ++i)
                dist_s[r4 * NPTS + tid + 256 * i] = xxn[r] + xxm[i] - 2.f * acc[r][i];
        }
        __syncthreads();

        // -------- per-wave selection of row n0 + p*4 + wave --------
        int n = n0 + p * 4 + wave;
        float v[32];
#pragma unroll
        for (int i = 0; i < 32; ++i) v[i] = dist_s[wave * NPTS + lane + 64 * i];
        int* outp = idxout + ((long)b * NPTS + n) * KNN;

        // threshold: T = max over 32 pair-minima (pairs lane^1)
        float lm = v[0];
#pragma unroll
        for (int i = 1; i < 32; ++i) lm = fminf(lm, v[i]);
        float pm = fminf(lm, __shfl_xor(lm, 1, 64));
        float T = pm;
#pragma unroll
        for (int off = 2; off < 64; off <<= 1) T = fmaxf(T, __shfl_xor(T, off, 64));

        // compact candidates (v <= T) into reused row region of dist_s
        float* cand_v = dist_s + wave * NPTS;          // [0..511]
        int* cand_i = (int*)(dist_s + wave * NPTS) + 512;  // [512..1023]
        int base = 0;
#pragma unroll
        for (int i = 0; i < 32; ++i) {
            bool pred = v[i] <= T;
            unsigned long long mask = __ballot(pred);
            int prefix = __builtin_amdgcn_mbcnt_hi(
                (unsigned)(mask >> 32),
                __builtin_amdgcn_mbcnt_lo((unsigned)mask, 0));
            if (pred) {
                int pos = base + prefix;
                if (pos < 512) { cand_v[pos] = v[i]; cand_i[pos] = lane + 64 * i; }
            }
            base += (int)__popcll(mask);
        }
        int M = base;

        if (M > 512) {
            // exact fallback (rare): original slow path on v[32]
            for (int kk = 0; kk < KNN; ++kk) {
                float bv = v[0];
                int bi = 0;
#pragma unroll
                for (int i = 1; i < 32; ++i)
                    if (v[i] < bv) { bv = v[i]; bi = i; }
                int bm = lane + 64 * bi;
#pragma unroll
                for (int off = 32; off >= 1; off >>= 1) {
                    float ov = __shfl_xor(bv, off, 64);
                    int om = __shfl_xor(bm, off, 64);
                    if (ov < bv || (ov == bv && om < bm)) { bv = ov; bm = om; }
                }
                if (lane == 0) outp[kk] = bm;
#pragma unroll
                for (int i = 0; i < 32; ++i)
                    if (bm == lane + 64 * i) v[i] = 3.0e38f;
            }
        } else {
            // pad to multiple of 64
            for (int t = M + lane; t < ((M + 63) & ~63); t += 64) cand_v[t] = 3.0e38f;
            int S = (M + 63) >> 6;  // 1..8, wave-uniform
            float cv[8];
            int ci[8];
#pragma unroll
            for (int j = 0; j < 8; ++j) { cv[j] = 3.0e38f; ci[j] = 0; }
#pragma unroll
            for (int j = 0; j < 8; ++j)
                if (j < S) { cv[j] = cand_v[lane + 64 * j]; ci[j] = cand_i[lane + 64 * j]; }

            for (int kk = 0; kk < KNN; ++kk) {
                float bv = cv[0];
                int bi = ci[0];
                int bp = lane;  // pos = lane + 64*j; pos order == column order
#pragma unroll
                for (int j = 1; j < 8; ++j)
                    if (j < S) {
                        if (cv[j] < bv) { bv = cv[j]; bi = ci[j]; bp = lane + 64 * j; }
                    }
#pragma unroll
                for (int off = 32; off >= 1; off >>= 1) {
                    float ov = __shfl_xor(bv, off, 64);
                    int oi = __shfl_xor(bi, off, 64);
                    int opp = __shfl_xor(bp, off, 64);
                    if (ov < bv || (ov == bv && opp < bp)) { bv = ov; bi = oi; bp = opp; }
                }
                if (lane == 0) outp[kk] = bi;
                int j0 = bp >> 6, l0 = bp & 63;  // wave-uniform
#pragma unroll
                for (int j = 0; j < 8; ++j)
                    if (j == j0 && lane == l0) cv[j] = 3.0e38f;
            }
        }
    }
}

// ============================================================
// t' = bn_scale*(W1-W2)@x + bn_bias ; u' = bn_scale*W2@x
// Block: 16 o x 256 n, thread: 16 o x 1 n. grid (NPTS/256, O/16, B)
// ============================================================
__global__ __launch_bounds__(256) void gemm_tu_kernel(
    const float* __restrict__ xin, long bstride, const float* __restrict__ W,
    const float* __restrict__ bg, const float* __restrict__ bb,
    const float* __restrict__ bm, const float* __restrict__ bv,
    float* __restrict__ tbuf, float* __restrict__ ubuf, int C, int O) {
    __shared__ float wa_s[128 * 16];  // (W1-W2)[c][ol]
    __shared__ float wb_s[128 * 16];  // W2[c][ol]
    int b = blockIdx.z;
    int o0 = blockIdx.y * 16;
    int n0 = blockIdx.x * 256;
    int tid = threadIdx.x;

    for (int i = tid; i < C * 16; i += 256) {
        int c = i >> 4, ol = i & 15;
        float w1 = W[(long)(o0 + ol) * (2 * C) + c];
        float w2 = W[(long)(o0 + ol) * (2 * C) + C + c];
        wa_s[i] = w1 - w2;
        wb_s[i] = w2;
    }
    __syncthreads();

    float ta[16], ua[16];
#pragma unroll
    for (int ol = 0; ol < 16; ++ol) { ta[ol] = 0.f; ua[ol] = 0.f; }

    const float* xb = xin + (long)b * bstride;
    for (int c = 0; c < C; ++c) {
        float xv = xb[(long)c * NPTS + n0 + tid];
        const float* wac = wa_s + c * 16;
        const float* wbc = wb_s + c * 16;
#pragma unroll
        for (int ol = 0; ol < 16; ++ol) {
            ta[ol] = fmaf(wac[ol], xv, ta[ol]);
            ua[ol] = fmaf(wbc[ol], xv, ua[ol]);
        }
    }

#pragma unroll
    for (int ol = 0; ol < 16; ++ol) {
        int o = o0 + ol;
        float sc = bg[o] / sqrtf(bv[o] + EPS_BN);
        float bias = bb[o] - bm[o] * sc;
        long base = ((long)b * O + o) * NPTS + n0 + tid;
        tbuf[base] = ta[ol] * sc + bias;
        ubuf[base] = ua[ol] * sc;
    }
}

// ============================================================
// out[b][o][n] = max_j lrelu(t'[b][o][n] + u'[b][o][idx[b][n][j]])
// grid (O, 2, B); block stages u' row in LDS, processes 1024 n (4/thread)
// ============================================================
__global__ __launch_bounds__(256) void gather_kernel(const float* __restrict__ tbuf,
                                                     const float* __restrict__ ubuf,
                                                     const int* __restrict__ idx,
                                                     float* __restrict__ out, int O) {
    __shared__ float urow[NPTS];
    int o = blockIdx.x, half = blockIdx.y, b = blockIdx.z;
    int tid = threadIdx.x;
    const float4* up4 = (const float4*)(ubuf + ((long)b * O + o) * NPTS);
    float4* ur4 = (float4*)urow;
    for (int i = tid; i < NPTS / 4; i += 256) ur4[i] = up4[i];
    __syncthreads();

    const float* tp = tbuf + ((long)b * O + o) * NPTS;
    float* op = out + (long)b * (512 * NPTS) + (long)o * NPTS;
    int n = half * 1024 + tid * 4;
    float4 tv4 = *(const float4*)(tp + n);
    float tv[4] = {tv4.x, tv4.y, tv4.z, tv4.w};
    float res[4];
#pragma unroll
    for (int q = 0; q < 4; ++q) {
        const int4* ip = (const int4*)(idx + ((long)b * NPTS + n + q) * KNN);
        float mx = -3.0e38f;
#pragma unroll
        for (int jj = 0; jj < 5; ++jj) {
            int4 i4 = ip[jj];
            float y0 = tv[q] + urow[i4.x];
            float y1 = tv[q] + urow[i4.y];
            float y2 = tv[q] + urow[i4.z];
            float y3 = tv[q] + urow[i4.w];
            y0 = y0 > 0.f ? y0 : 0.2f * y0;
            y1 = y1 > 0.f ? y1 : 0.2f * y1;
            y2 = y2 > 0.f ? y2 : 0.2f * y2;
            y3 = y3 > 0.f ? y3 : 0.2f * y3;
            mx = fmaxf(mx, fmaxf(fmaxf(y0, y1), fmaxf(y2, y3)));
        }
        res[q] = mx;
    }
    *(float4*)(op + n) = make_float4(res[0], res[1], res[2], res[3]);
}

// ============================================================
// emb = lrelu(bn5(W5 @ xc)); partial max/sum over n-half.
// grid (1024/16, 2, B)
// ============================================================
__global__ __launch_bounds__(256) void w5_reduce_kernel(
    const float* __restrict__ xc, const float* __restrict__ W5,
    const float* __restrict__ bg, const float* __restrict__ bb,
    const float* __restrict__ bm, const float* __restrict__ bv,
    float* __restrict__ pmax, float* __restrict__ psum) {
    __shared__ float w_s[512 * 16];  // 32 KB, [c][ol]
    __shared__ float rmax[4][16];
    __shared__ float rsum[4][16];
    int b = blockIdx.z;
    int half = blockIdx.y;
    int o0 = blockIdx.x * 16;
    int tid = threadIdx.x;

    for (int i = tid; i < 512 * 16; i += 256) {
        int c = i >> 4, ol = i & 15;
        w_s[i] = W5[(long)(o0 + ol) * 512 + c];
    }
    __syncthreads();

    float acc[4][16];
#pragma unroll
    for (int v = 0; v < 4; ++v)
#pragma unroll
        for (int ol = 0; ol < 16; ++ol) acc[v][ol] = 0.f;

    const float* xb = xc + (long)b * 512 * NPTS + half * 1024;
    for (int c = 0; c < 512; ++c) {
        const float* row = xb + (long)c * NPTS;
        float xv0 = row[tid];
        float xv1 = row[tid + 256];
        float xv2 = row[tid + 512];
        float xv3 = row[tid + 768];
        const float* wc = w_s + c * 16;
#pragma unroll
        for (int ol = 0; ol < 16; ++ol) {
            float w = wc[ol];
            acc[0][ol] = fmaf(w, xv0, acc[0][ol]);
            acc[1][ol] = fmaf(w, xv1, acc[1][ol]);
            acc[2][ol] = fmaf(w, xv2, acc[2][ol]);
            acc[3][ol] = fmaf(w, xv3, acc[3][ol]);
        }
    }

    float mx[16], sm[16];
#pragma unroll
    for (int ol = 0; ol < 16; ++ol) {
        int o = o0 + ol;
        float sc = bg[o] / sqrtf(bv[o] + EPS_BN);
        float bi = bb[o] - bm[o] * sc;
        float m = -3.0e38f, s = 0.f;
#pragma unroll
        for (int v = 0; v < 4; ++v) {
            float y = acc[v][ol] * sc + bi;
            y = y > 0.f ? y : 0.2f * y;
            m = fmaxf(m, y);
            s += y;
        }
        mx[ol] = m;
        sm[ol] = s;
    }

    int wave = tid >> 6, lane = tid & 63;
#pragma unroll
    for (int ol = 0; ol < 16; ++ol) {
        float m = mx[ol], s = sm[ol];
#pragma unroll
        for (int off = 32; off >= 1; off >>= 1) {
            m = fmaxf(m, __shfl_xor(m, off, 64));
            s += __shfl_xor(s, off, 64);
        }
        mx[ol] = m;
        sm[ol] = s;
    }
    if (lane == 0) {
#pragma unroll
        for (int ol = 0; ol < 16; ++ol) { rmax[wave][ol] = mx[ol]; rsum[wave][ol] = sm[ol]; }
    }
    __syncthreads();
    if (tid < 16) {
        float m = rmax[0][tid], s = rsum[0][tid];
#pragma unroll
        for (int w = 1; w < 4; ++w) { m = fmaxf(m, rmax[w][tid]); s += rsum[w][tid]; }
        long base = ((long)half * 8 + b) * 1024 + o0 + tid;
        pmax[base] = m;
        psum[base] = s;
    }
}

// combine halves -> feat[b][0..1023]=max, feat[b][1024..2047]=mean
__global__ __launch_bounds__(256) void w5_combine_kernel(const float* __restrict__ pmax,
                                                         const float* __restrict__ psum,
                                                         float* __restrict__ feat) {
    int b = blockIdx.x;
    for (int o = threadIdx.x; o < 1024; o += 256) {
        float m = fmaxf(pmax[(long)b * 1024 + o], pmax[(long)(8 + b) * 1024 + o]);
        float s = psum[(long)b * 1024 + o] + psum[(long)(8 + b) * 1024 + o];
        feat[(long)b * 2048 + o] = m;
        feat[(long)b * 2048 + 1024 + o] = s * (1.f / 2048.f);
    }
}

// ============================================================
// Generic FC: out[b][o] = act(bn(in[b] . W[o]))  (wave per o)
// ============================================================
__global__ __launch_bounds__(256) void fc_kernel(const float* __restrict__ in,
                                                 const float* __restrict__ W,
                                                 const float* __restrict__ bg,
                                                 const float* __restrict__ bb,
                                                 const float* __restrict__ bm,
                                                 const float* __restrict__ bv,
                                                 float* __restrict__ out, int I, int O,
                                                 int do_lrelu) {
    int b = blockIdx.y;
    int o = blockIdx.x * 4 + (threadIdx.x >> 6);
    int lane = threadIdx.x & 63;
    if (o < O) {
        const float* ip = in + (long)b * I;
        const float* wp = W + (long)o * I;
        float s = 0.f;
        for (int i = lane; i < I; i += 64) s = fmaf(ip[i], wp[i], s);
#pragma unroll
        for (int off = 32; off >= 1; off >>= 1) s += __shfl_xor(s, off, 64);
        if (lane == 0) {
            float y;
            if (bg) {
                float scv = bg[o] / sqrtf(bv[o] + EPS_BN);
                y = (s - bm[o]) * scv + bb[o];
                if (do_lrelu) y = y > 0.f ? y : 0.2f * y;
            } else {
                y = s + bb[o];
            }
            out[(long)b * O + o] = y;
        }
    }
}

// ============================================================
extern "C" void kernel_launch(void* const* d_in, const int* in_sizes, int n_in,
                              void* d_out, int out_size, void* d_ws, size_t ws_size,
                              hipStream_t stream) {
    const float* x = (const float*)d_in[0];
    const float* W1 = (const float*)d_in[1];
    const float* W2 = (const float*)d_in[6];
    const float* W3 = (const float*)d_in[11];
    const float* W4 = (const float*)d_in[16];
    const float* W5 = (const float*)d_in[21];
    const float* L1 = (const float*)d_in[26];
    const float* L2 = (const float*)d_in[31];
    const float* L3 = (const float*)d_in[36];
    const float* L3b = (const float*)d_in[37];

    // workspace layout
    float* xc = (float*)d_ws;                         // 8*512*2048
    float* tb = xc + (long)8 * 512 * NPTS;            // 8*256*2048
    float* ub = tb + (long)8 * 256 * NPTS;            // 8*256*2048
    int* idx = (int*)(ub + (long)8 * 256 * NPTS);     // 8*2048*20
    float* xxb = (float*)(idx + (long)8 * NPTS * KNN);  // 8*2048
    float* feat = xxb + (long)8 * NPTS;               // 8*2048
    float* h1 = feat + (long)8 * NPTS;                // 8*512
    float* h2 = h1 + (long)8 * 512;                   // 8*256
    // pmax/psum reuse tb region (tb/ub dead after layer-4 gather)
    float* pmax = tb;                                 // 2*8*1024
    float* psum = tb + (long)2 * 8 * 1024;            // 2*8*1024

    struct Layer {
        const float* xin; long bstride; const float* W;
        const float *g, *b, *m, *v; int C, O, c0;
    };
    Layer layers[4] = {
        {x, (long)3 * NPTS, W1,
         (const float*)d_in[2], (const float*)d_in[3], (const float*)d_in[4], (const float*)d_in[5],
         3, 64, 0},
        {xc, (long)512 * NPTS, W2,
         (const float*)d_in[7], (const float*)d_in[8], (const float*)d_in[9], (const float*)d_in[10],
         64, 64, 64},
        {xc + (long)64 * NPTS, (long)512 * NPTS, W3,
         (const float*)d_in[12], (const float*)d_in[13], (const float*)d_in[14], (const float*)d_in[15],
         64, 128, 128},
        {xc + (long)128 * NPTS, (long)512 * NPTS, W4,
         (const float*)d_in[17], (const float*)d_in[18], (const float*)d_in[19], (const float*)d_in[20],
         128, 256, 256},
    };

    for (int l = 0; l < 4; ++l) {
        const Layer& L = layers[l];
        xx_kernel<<<dim3(NPTS / 256, 8), 256, 0, stream>>>(L.xin, L.bstride, xxb, L.C);
        dist_topk_kernel<<<dim3(NPTS / 8, 8), 256, 0, stream>>>(L.xin, L.bstride, xxb, idx, L.C);
        gemm_tu_kernel<<<dim3(NPTS / 256, L.O / 16, 8), 256, 0, stream>>>(
            L.xin, L.bstride, L.W, L.g, L.b, L.m, L.v, tb, ub, L.C, L.O);
        gather_kernel<<<dim3(L.O, 2, 8), 256, 0, stream>>>(tb, ub, idx, xc + (long)L.c0 * NPTS, L.O);
    }

    w5_reduce_kernel<<<dim3(1024 / 16, 2, 8), 256, 0, stream>>>(
        xc, W5, (const float*)d_in[22], (const float*)d_in[23], (const float*)d_in[24],
        (const float*)d_in[25], pmax, psum);
    w5_combine_kernel<<<dim3(8), 256, 0, stream>>>(pmax, psum, feat);

    fc_kernel<<<dim3(512 / 4, 8), 256, 0, stream>>>(
        feat, L1, (const float*)d_in[27], (const float*)d_in[28], (const float*)d_in[29],
        (const float*)d_in[30], h1, 2048, 512, 1);
    fc_kernel<<<dim3(256 / 4, 8), 256, 0, stream>>>(
        h1, L2, (const float*)d_in[32], (const float*)d_in[33], (const float*)d_in[34],
        (const float*)d_in[35], h2, 512, 256, 1);
    fc_kernel<<<dim3(10, 8), 256, 0, stream>>>(
        h2, L3, nullptr, L3b, nullptr, nullptr, (float*)d_out, 256, 40, 0);
}